// Round 8
// baseline (449.895 us; speedup 1.0000x reference)
//
#include <hip/hip_runtime.h>

// Linear attention, folded form, all GEMMs f16-MFMA + global_load_lds staging:
//   xh,wh     = f16(x), f16(w_map); whqT = f16(w_q)^T      (phase P)
//   ctx[b,h]  = (k_ln)^T (v_ln)                            (phase A, fused, 2 heads/block)
//   ThT[b]    = (blockdiag(ctx/n) @ w_out^T)^T in f16      (phase B1)
//   WcT[b]    = (w_q^T @ T[b])^T in f16                    (phase B2)
//   out[b]    = x[b] @ Wc[b] + b_out                       (phase C, BN=256)

typedef _Float16 f16;
typedef __attribute__((ext_vector_type(4))) _Float16 f16x4;
typedef __attribute__((ext_vector_type(8))) _Float16 f16x8;
typedef __attribute__((ext_vector_type(4))) float f32x4;

#define MFMA_F16(a, b, c) __builtin_amdgcn_mfma_f32_16x16x32_f16((a), (b), (c), 0, 0, 0)

#define BATCH  8
#define NSEQ   4096
#define DIM    768
#define HEADS  12
#define DH     64
#define KOFF   768
#define VOFF   1536
#define EPS    1e-5f

// LDS tile rows are 128B (64 f16). Content is XOR-swizzled on 16B chunks by
// (row&7): LDS[row][b] holds global[row][b ^ ((row&7)<<4)]. global_load_lds
// writes LINEARLY (wave base + lane*16), so the swizzle is applied to the
// per-lane GLOBAL source address (rule #21), and reads use SWZ below.
#define SWZ(row, byte) ((row) * 128 + ((byte) ^ (((row) & 7) << 4)))
#define SWZ256(row, byte) ((row) * 256 + ((byte) ^ (((row) & 7) << 4)))

__device__ __forceinline__ void gl16(const void* g, void* l) {
    __builtin_amdgcn_global_load_lds(
        (const __attribute__((address_space(1))) void*)g,
        (__attribute__((address_space(3))) void*)l, 16, 0, 0);
}

// ---------------------------------------------------------------------------
// Phase P: fp32 -> f16 convert (grid-stride, 8 elems/thread)
// ---------------------------------------------------------------------------
__global__ void convert_kernel(const float* __restrict__ src,
                               f16* __restrict__ dst, size_t n8)
{
    size_t i = (size_t)blockIdx.x * blockDim.x + threadIdx.x;
    size_t stride = (size_t)gridDim.x * blockDim.x;
    for (; i < n8; i += stride) {
        const float4* s = (const float4*)(src + i * 8);
        float4 v0 = s[0], v1 = s[1];
        f16x8 h = { (f16)v0.x, (f16)v0.y, (f16)v0.z, (f16)v0.w,
                    (f16)v1.x, (f16)v1.y, (f16)v1.z, (f16)v1.w };
        *(f16x8*)(dst + i * 8) = h;
    }
}

// Phase P2: whqT[c][hd] = f16(w_map[hd][c]), hd,c in [0,768). grid (12,12).
__global__ void transp_q_kernel(const float* __restrict__ w_map,
                                f16* __restrict__ whqT)
{
    __shared__ f16 tl[64][80];
    const int tid = threadIdx.x;
    const int hd0 = blockIdx.x * 64, c0 = blockIdx.y * 64;
    #pragma unroll
    for (int t = 0; t < 4; ++t) {
        int idx = tid + t * 256;
        int r = idx >> 4, c4 = (idx & 15) << 2;
        float4 v = *(const float4*)(w_map + (size_t)(hd0 + r) * DIM + c0 + c4);
        tl[c4 + 0][r] = (f16)v.x;
        tl[c4 + 1][r] = (f16)v.y;
        tl[c4 + 2][r] = (f16)v.z;
        tl[c4 + 3][r] = (f16)v.w;
    }
    __syncthreads();
    #pragma unroll
    for (int t = 0; t < 2; ++t) {
        int idx = tid + t * 256;
        int c = idx >> 3, p = idx & 7;
        f16x8 hv = *(f16x8*)&tl[c][p * 8];
        *(f16x8*)(whqT + (size_t)(c0 + c) * DIM + hd0 + p * 8) = hv;
    }
}

// ---------------------------------------------------------------------------
// Phase A: 2 heads per block. proj GEMM (128n x 256cols = k_h0|v_h0|k_h1|v_h1)
// -> in-register LN -> per-head transposed f16 LDS -> ctx MFMA -> atomics.
// grid (32, 6, 8), block 512 (8 waves 2x4).
// ---------------------------------------------------------------------------
__launch_bounds__(512, 4)
__global__ void kv_ctx_kernel(const f16* __restrict__ xh,
                              const f16* __restrict__ wh,
                              const float* __restrict__ g_k,
                              const float* __restrict__ b_k,
                              const float* __restrict__ g_v,
                              const float* __restrict__ b_v,
                              float* __restrict__ ctx)
{
    __shared__ __align__(16) char smem[49152];   // xs 16KB @0, ws 32KB @16K
                                                 // ctx phase: kT @0, vT @16K

    const int tid  = threadIdx.x;
    const int lane = tid & 63;
    const int w    = tid >> 6;      // wave 0..7
    const int wr   = w >> 2;        // n-half
    const int wcq  = w & 3;         // col quadrant: 0=k_h0 1=v_h0 2=k_h1 3=v_h1
    const int l15  = lane & 15;
    const int hi   = lane >> 4;
    const int lr   = lane >> 3;            // 0..7 row-in-8
    const int lb   = (lane & 7) << 4;      // byte-in-row
    const int srcB = lb ^ (lr << 4);       // inverse-swizzled source byte
    const int n0   = blockIdx.x * 128;
    const int h0   = blockIdx.y * 2;
    const int bb   = blockIdx.z;

    // x staging: 2 issues/wave, rows w*16 + i*8 + lr
    const char* px = (const char*)xh
        + ((size_t)(bb * NSEQ + n0 + w * 16 + lr) * DIM) * 2 + srcB;
    // w staging: 4 issues/wave, tile rows w*32 + i*8 + lr (64-row segments)
    const char* pw[4];
    #pragma unroll
    for (int i = 0; i < 4; ++i) {
        int kvr = w * 32 + i * 8 + lr;     // 0..255
        int seg = kvr >> 6;                // 0=k_h0 1=v_h0 2=k_h1 3=v_h1
        int wrow = ((seg & 1) ? VOFF : KOFF) + (h0 + (seg >> 1)) * DH + (kvr & 63);
        pw[i] = (const char*)wh + ((size_t)wrow * DIM) * 2 + srcB;
    }
    char* dxb = smem + w * 2048;           // + i*1024
    char* dwb = smem + 16384 + w * 4096;   // + i*1024

    f32x4 acc[4][4];
    #pragma unroll
    for (int m = 0; m < 4; ++m)
        #pragma unroll
        for (int n = 0; n < 4; ++n)
            acc[m][n] = (f32x4)(0.f);

    for (int c0 = 0; c0 < DIM; c0 += 64) {
        __syncthreads();
        const int kbyt = c0 * 2;
        #pragma unroll
        for (int i = 0; i < 2; ++i)
            gl16(px + kbyt + i * 12288, dxb + i * 1024);
        #pragma unroll
        for (int i = 0; i < 4; ++i)
            gl16(pw[i] + kbyt, dwb + i * 1024);
        __syncthreads();
        #pragma unroll
        for (int kk = 0; kk < 2; ++kk) {
            const int kb = (kk * 32 + hi * 8) * 2;
            f16x8 a[4], b[4];
            #pragma unroll
            for (int m = 0; m < 4; ++m) {
                int row = wr * 64 + m * 16 + l15;
                a[m] = *(const f16x8*)(smem + SWZ(row, kb));
            }
            #pragma unroll
            for (int n = 0; n < 4; ++n) {
                int row = wcq * 64 + n * 16 + l15;
                b[n] = *(const f16x8*)(smem + 16384 + SWZ(row, kb));
            }
            #pragma unroll
            for (int m = 0; m < 4; ++m)
                #pragma unroll
                for (int n = 0; n < 4; ++n)
                    acc[m][n] = MFMA_F16(a[m], b[n], acc[m][n]);
        }
    }
    __syncthreads();   // staging LDS dead; tbuf reuse begins

    // ---- LN params for this wave's quadrant (one head's k or v, 64 features)
    const int  isv  = wcq & 1;
    const int  myhp = wcq >> 1;
    const float* gp = isv ? g_v : g_k;
    const float* bp = isv ? b_v : b_k;
    float gg[4], be[4];
    #pragma unroll
    for (int n = 0; n < 4; ++n) { gg[n] = gp[n * 16 + l15]; be[n] = bp[n * 16 + l15]; }

    // ---- two head passes: LN-write (owning waves) -> ctx MFMA (all) -> atomics
    for (int hpass = 0; hpass < 2; ++hpass) {
        if (myhp == hpass) {
            char* tbuf = smem + isv * 16384;   // kT @0, vT @16K  [64 feat][128 n]
            #pragma unroll
            for (int m = 0; m < 4; ++m) {
                float o[4][4];                 // [reg][nfrag]
                #pragma unroll
                for (int r = 0; r < 4; ++r) {
                    float s = 0.f, ss = 0.f;
                    #pragma unroll
                    for (int n = 0; n < 4; ++n) { float t = acc[m][n][r]; s += t; ss += t * t; }
                    s += __shfl_xor(s, 1); ss += __shfl_xor(ss, 1);
                    s += __shfl_xor(s, 2); ss += __shfl_xor(ss, 2);
                    s += __shfl_xor(s, 4); ss += __shfl_xor(ss, 4);
                    s += __shfl_xor(s, 8); ss += __shfl_xor(ss, 8);
                    float mu  = s * (1.f / DH);
                    float var = ss * (1.f / DH) - mu * mu;
                    float rs  = rsqrtf(var + EPS);
                    #pragma unroll
                    for (int n = 0; n < 4; ++n)
                        o[r][n] = (acc[m][n][r] - mu) * rs * gg[n] + be[n];
                }
                const int nrow0 = wr * 64 + m * 16 + hi * 4;
                #pragma unroll
                for (int n = 0; n < 4; ++n) {
                    int col = n * 16 + l15;
                    f16x4 hv = { (f16)o[0][n], (f16)o[1][n], (f16)o[2][n], (f16)o[3][n] };
                    *(f16x4*)(tbuf + SWZ256(col, nrow0 * 2)) = hv;
                }
            }
        }
        __syncthreads();

        // ctx 64x64 over K=128 n-rows; wave: d-strip (w&3)*16, e-half (w>>2)*32
        f32x4 c2[2];
        c2[0] = (f32x4)(0.f); c2[1] = (f32x4)(0.f);
        #pragma unroll
        for (int ks = 0; ks < 4; ++ks) {
            const int kb = (ks * 32 + hi * 8) * 2;
            int drow = (w & 3) * 16 + l15;
            f16x8 ak = *(const f16x8*)(smem + SWZ256(drow, kb));
            #pragma unroll
            for (int ef = 0; ef < 2; ++ef) {
                int col = (w >> 2) * 32 + ef * 16 + l15;
                f16x8 bv = *(const f16x8*)(smem + 16384 + SWZ256(col, kb));
                c2[ef] = MFMA_F16(ak, bv, c2[ef]);
            }
        }
        float* cbase = ctx + (size_t)(bb * HEADS + h0 + hpass) * DH * DH;
        #pragma unroll
        for (int ef = 0; ef < 2; ++ef)
            #pragma unroll
            for (int r = 0; r < 4; ++r) {
                int d  = (w & 3) * 16 + hi * 4 + r;
                int ee = (w >> 2) * 32 + ef * 16 + l15;
                atomicAdd(cbase + d * DH + ee, c2[ef][r]);
            }
        __syncthreads();   // tbuf reused by next pass
    }
}

// ---------------------------------------------------------------------------
// Phase B1: ThT[b, j, h*64+d] = sum_e (ctx[b,h,d,e]/n) * w_out[j, h*64+e]
// grid (3, HEADS, BATCH), block 256.
// ---------------------------------------------------------------------------
__launch_bounds__(256)
__global__ void ctx_wout_kernel(const float* __restrict__ ctx,
                                const float* __restrict__ w_out,
                                f16* __restrict__ ThT)
{
    __shared__ float cs[DH * DH];
    const int tid = threadIdx.x;
    const int jt = blockIdx.x, h = blockIdx.y, bb = blockIdx.z;
    const float scale = 1.f / NSEQ;
    const float* cbase = ctx + (size_t)(bb * HEADS + h) * DH * DH;
    for (int t = tid; t < DH * DH; t += 256) cs[t] = cbase[t] * scale;
    __syncthreads();

    const int j = jt * 256 + tid;
    float wv[DH];
    const float* wrow = w_out + (size_t)j * DIM + h * DH;
    #pragma unroll
    for (int e4 = 0; e4 < DH; e4 += 4) {
        float4 v = *(const float4*)(wrow + e4);
        wv[e4] = v.x; wv[e4 + 1] = v.y; wv[e4 + 2] = v.z; wv[e4 + 3] = v.w;
    }
    f16* trow = ThT + ((size_t)bb * DIM + j) * DIM + h * DH;
    for (int d = 0; d < DH; ++d) {
        float a = 0.f;
        #pragma unroll
        for (int e = 0; e < DH; ++e) a += cs[d * DH + e] * wv[e];
        trow[d] = (f16)a;
    }
}

// ---------------------------------------------------------------------------
// Phase B2: WcT[b][j][c] = sum_hd ThT[b,j,hd] * whqT[c,hd]  (MFMA, gl_lds)
// grid (6, 6, 8), block 256.
// ---------------------------------------------------------------------------
__launch_bounds__(256, 2)
__global__ void fold_q_kernel(const f16* __restrict__ ThT,
                              const f16* __restrict__ whqT,
                              f16* __restrict__ WcT)
{
    __shared__ __align__(16) char smem[32768];

    const int tid  = threadIdx.x;
    const int lane = tid & 63;
    const int w    = tid >> 6;
    const int wr   = w >> 1, wc = w & 1;
    const int l15  = lane & 15, hi = lane >> 4;
    const int lr   = lane >> 3;
    const int lb   = (lane & 7) << 4;
    const int srcB = lb ^ (lr << 4);
    const int j0   = blockIdx.x * 128;
    const int c0g  = blockIdx.y * 128;
    const int bb   = blockIdx.z;

    const char* pa = (const char*)ThT
        + ((size_t)(bb * DIM + j0 + w * 32 + lr) * DIM) * 2 + srcB;
    const char* pb = (const char*)whqT
        + ((size_t)(c0g + w * 32 + lr) * DIM) * 2 + srcB;
    char* dab = smem + w * 4096;
    char* dbb = smem + 16384 + w * 4096;

    f32x4 acc[4][4];
    #pragma unroll
    for (int m = 0; m < 4; ++m)
        #pragma unroll
        for (int n = 0; n < 4; ++n)
            acc[m][n] = (f32x4)(0.f);

    for (int k0 = 0; k0 < DIM; k0 += 64) {
        __syncthreads();
        const int kbyt = k0 * 2;
        #pragma unroll
        for (int i = 0; i < 4; ++i) {
            gl16(pa + kbyt + i * 12288, dab + i * 1024);
            gl16(pb + kbyt + i * 12288, dbb + i * 1024);
        }
        __syncthreads();
        #pragma unroll
        for (int kk = 0; kk < 2; ++kk) {
            const int kb = (kk * 32 + hi * 8) * 2;
            f16x8 a[4], b[4];
            #pragma unroll
            for (int m = 0; m < 4; ++m) {
                int row = wr * 64 + m * 16 + l15;
                a[m] = *(const f16x8*)(smem + SWZ(row, kb));
            }
            #pragma unroll
            for (int n = 0; n < 4; ++n) {
                int col = wc * 64 + n * 16 + l15;
                b[n] = *(const f16x8*)(smem + 16384 + SWZ(col, kb));
            }
            #pragma unroll
            for (int m = 0; m < 4; ++m)
                #pragma unroll
                for (int n = 0; n < 4; ++n)
                    acc[m][n] = MFMA_F16(a[m], b[n], acc[m][n]);
        }
    }

    f16* ob = WcT + (size_t)bb * DIM * DIM;
    #pragma unroll
    for (int m = 0; m < 4; ++m)
        #pragma unroll
        for (int n = 0; n < 4; ++n)
            #pragma unroll
            for (int r = 0; r < 4; ++r) {
                int j = j0 + wr * 64 + m * 16 + hi * 4 + r;
                int c = c0g + wc * 64 + n * 16 + l15;
                ob[(size_t)j * DIM + c] = (f16)acc[m][n][r];
            }
}

// ---------------------------------------------------------------------------
// Phase C: out[b] = x[b] @ Wc[b] + b_out   (MFMA, gl_lds, BN=256)
// grid (32, 3, 8), block 512 (8 waves 2x4).
// ---------------------------------------------------------------------------
__launch_bounds__(512, 4)
__global__ void final_gemm_kernel(const f16* __restrict__ xh,
                                  const f16* __restrict__ WcT,
                                  const float* __restrict__ b_out,
                                  float* __restrict__ out)
{
    __shared__ __align__(16) char smem[49152];   // xs 16KB @0, Wc 32KB @16K

    const int tid  = threadIdx.x;
    const int lane = tid & 63;
    const int w    = tid >> 6;      // 0..7
    const int wr   = w >> 2, wcq = w & 3;
    const int l15  = lane & 15, hi = lane >> 4;
    const int lr   = lane >> 3;
    const int lb   = (lane & 7) << 4;
    const int srcB = lb ^ (lr << 4);
    const int n0   = blockIdx.x * 128;
    const int j0   = blockIdx.y * 256;
    const int bb   = blockIdx.z;

    const char* pa = (const char*)xh
        + ((size_t)(bb * NSEQ + n0 + w * 16 + lr) * DIM) * 2 + srcB;
    const char* pb = (const char*)WcT
        + ((size_t)(bb * DIM + j0 + w * 32 + lr) * DIM) * 2 + srcB;
    char* dab = smem + w * 2048;           // + i*1024, i<2
    char* dbb = smem + 16384 + w * 4096;   // + i*1024, i<4

    f32x4 acc[4][4];
    #pragma unroll
    for (int m = 0; m < 4; ++m)
        #pragma unroll
        for (int n = 0; n < 4; ++n)
            acc[m][n] = (f32x4)(0.f);

    for (int c0 = 0; c0 < DIM; c0 += 64) {
        __syncthreads();
        const int kbyt = c0 * 2;
        #pragma unroll
        for (int i = 0; i < 2; ++i)
            gl16(pa + kbyt + i * 12288, dab + i * 1024);
        #pragma unroll
        for (int i = 0; i < 4; ++i)
            gl16(pb + kbyt + i * 12288, dbb + i * 1024);
        __syncthreads();
        #pragma unroll
        for (int kk = 0; kk < 2; ++kk) {
            const int kb = (kk * 32 + hi * 8) * 2;
            f16x8 a[4], b[4];
            #pragma unroll
            for (int m = 0; m < 4; ++m) {
                int row = wr * 64 + m * 16 + l15;
                a[m] = *(const f16x8*)(smem + SWZ(row, kb));
            }
            #pragma unroll
            for (int n = 0; n < 4; ++n) {
                int row = wcq * 64 + n * 16 + l15;
                b[n] = *(const f16x8*)(smem + 16384 + SWZ(row, kb));
            }
            #pragma unroll
            for (int m = 0; m < 4; ++m)
                #pragma unroll
                for (int n = 0; n < 4; ++n)
                    acc[m][n] = MFMA_F16(a[m], b[n], acc[m][n]);
        }
    }

    float bias[4];
    #pragma unroll
    for (int n = 0; n < 4; ++n) bias[n] = b_out[j0 + wcq * 64 + n * 16 + l15];

    float* ob = out + ((size_t)bb * NSEQ + n0) * DIM;
    #pragma unroll
    for (int m = 0; m < 4; ++m)
        #pragma unroll
        for (int n = 0; n < 4; ++n)
            #pragma unroll
            for (int r = 0; r < 4; ++r) {
                int rn = wr * 64 + m * 16 + hi * 4 + r;
                int cj = j0 + wcq * 64 + n * 16 + l15;
                ob[(size_t)rn * DIM + cj] = acc[m][n][r] + bias[n];
            }
}

// ---------------------------------------------------------------------------
extern "C" void kernel_launch(void* const* d_in, const int* in_sizes, int n_in,
                              void* d_out, int out_size, void* d_ws, size_t ws_size,
                              hipStream_t stream)
{
    (void)in_sizes; (void)n_in; (void)out_size; (void)ws_size;
    const float* x     = (const float*)d_in[0];
    const float* w_map = (const float*)d_in[1];
    const float* g_k   = (const float*)d_in[2];
    const float* b_k   = (const float*)d_in[3];
    const float* g_v   = (const float*)d_in[4];
    const float* b_v   = (const float*)d_in[5];
    const float* w_out = (const float*)d_in[6];
    const float* b_out = (const float*)d_in[7];
    float* out = (float*)d_out;

    // workspace: ctx f32 | xh f16 | wh f16 | whqT f16 | ThT f16 | WcT f16
    char* wsb  = (char*)d_ws;
    float* ctx = (float*)wsb;                       wsb += (size_t)BATCH * HEADS * DH * DH * 4;
    f16* xh    = (f16*)wsb;                         wsb += (size_t)BATCH * NSEQ * DIM * 2;
    f16* wh    = (f16*)wsb;                         wsb += (size_t)3 * DIM * DIM * 2;
    f16* whqT  = (f16*)wsb;                         wsb += (size_t)DIM * DIM * 2;
    f16* ThT   = (f16*)wsb;                         wsb += (size_t)BATCH * DIM * DIM * 2;
    f16* WcT   = (f16*)wsb;

    hipMemsetAsync(ctx, 0, (size_t)BATCH * HEADS * DH * DH * sizeof(float), stream);

    convert_kernel<<<2048, 256, 0, stream>>>(x, xh, (size_t)BATCH * NSEQ * DIM / 8);
    convert_kernel<<<864, 256, 0, stream>>>(w_map, wh, (size_t)3 * DIM * DIM / 8);
    dim3 gT(12, 12);
    transp_q_kernel<<<gT, 256, 0, stream>>>(w_map, whqT);

    dim3 gA(NSEQ / 128, HEADS / 2, BATCH);
    kv_ctx_kernel<<<gA, 512, 0, stream>>>(xh, wh, g_k, b_k, g_v, b_v, ctx);

    dim3 gB1(DIM / 256, HEADS, BATCH);
    ctx_wout_kernel<<<gB1, 256, 0, stream>>>(ctx, w_out, ThT);

    dim3 gB2(DIM / 128, DIM / 128, BATCH);
    fold_q_kernel<<<gB2, 256, 0, stream>>>(ThT, whqT, WcT);

    dim3 gC(NSEQ / 128, DIM / 256, BATCH);
    final_gemm_kernel<<<gC, 512, 0, stream>>>(xh, WcT, b_out, out);
}